// Round 2
// baseline (520.680 us; speedup 1.0000x reference)
//
#include <hip/hip_runtime.h>
#include <hip/hip_bf16.h>

#define NN 8192
#define DD 128
#define CC 10
#define TT 1024

typedef __attribute__((ext_vector_type(8))) short bf16x8;   // 8 bf16 in 4 VGPRs
typedef __attribute__((ext_vector_type(4))) short bf16x4;   // 4 bf16 in 2 VGPRs
typedef __attribute__((ext_vector_type(4))) float f32x4;

__device__ __forceinline__ void gload16(const void* g, void* l) {
  __builtin_amdgcn_global_load_lds(
      (const __attribute__((address_space(1))) void*)g,
      (__attribute__((address_space(3))) void*)l, 16, 0, 0);
}

__device__ __forceinline__ bf16x4 cvt4(float a, float b, float c, float d) {
  __hip_bfloat16 t[4] = {__float2bfloat16(a), __float2bfloat16(b),
                         __float2bfloat16(c), __float2bfloat16(d)};
  return *(const bf16x4*)t;
}

// ---------------- K1: class head + softmax + coefficients + s row-major ----------------
__global__ __launch_bounds__(256) void k_head(
    const float* __restrict__ xr, const float* __restrict__ xi,
    const float* __restrict__ Wcr, const float* __restrict__ bcr,
    const float* __restrict__ Wci, const float* __restrict__ bci,
    const float* __restrict__ thr, const float* __restrict__ thi,
    const int* __restrict__ labels,
    __hip_bfloat16* __restrict__ s,       // [8192][256] bf16
    float* __restrict__ stats)            // [8192][4] = inr, ini, picked, lse
{
  const int lane = threadIdx.x & 63;
  const int i = blockIdx.x * 4 + (threadIdx.x >> 6);

  const float xr0 = xr[(size_t)i * DD + lane];
  const float xr1 = xr[(size_t)i * DD + 64 + lane];
  const float xi0 = xi[(size_t)i * DD + lane];
  const float xi1 = xi[(size_t)i * DD + 64 + lane];

  float pn[CC];
#pragma unroll
  for (int c = 0; c < CC; c++) {
    const float wr0 = Wcr[c * DD + lane];
    const float wr1 = Wcr[c * DD + 64 + lane];
    const float wi0 = Wci[c * DD + lane];
    const float wi1 = Wci[c * DD + 64 + lane];
    float u = xr0 * wr0 + xr1 * wr1 - xi0 * wi0 - xi1 * wi1;  // pa - pc
    float v = xi0 * wr0 + xi1 * wr1 + xr0 * wi0 + xr1 * wi1;  // pb + pd
#pragma unroll
    for (int off = 32; off > 0; off >>= 1) {
      u += __shfl_xor(u, off, 64);
      v += __shfl_xor(v, off, 64);
    }
    const float cr = u + bcr[c] - bci[c];
    const float ci = v + bcr[c] + bci[c];
    pn[c] = sqrtf(cr * cr + ci * ci);
  }
  float mx = pn[0];
#pragma unroll
  for (int c = 1; c < CC; c++) mx = fmaxf(mx, pn[c]);
  float ex[CC];
  float den = 0.f;
#pragma unroll
  for (int c = 0; c < CC; c++) { ex[c] = expf(pn[c] - mx); den += ex[c]; }
  float inr = 0.f, ini = 0.f;
#pragma unroll
  for (int c = 0; c < CC; c++) {
    const float sm = ex[c] / den;
    inr += sm * thr[c];
    ini += sm * thi[c];
  }
  // out = conj(in):  s_r = in_r*xr + in_i*xi ; s_i = in_r*xi - in_i*xr
  s[(size_t)i * 256 + lane]       = __float2bfloat16(inr * xr0 + ini * xi0);
  s[(size_t)i * 256 + 64 + lane]  = __float2bfloat16(inr * xr1 + ini * xi1);
  s[(size_t)i * 256 + 128 + lane] = __float2bfloat16(inr * xi0 - ini * xr0);
  s[(size_t)i * 256 + 192 + lane] = __float2bfloat16(inr * xi1 - ini * xr1);

  if (lane == 0) {
    const int lab = labels[i];
    float picked = pn[0];
#pragma unroll
    for (int c = 1; c < CC; c++) picked = (lab == c) ? pn[c] : picked;
    stats[i * 4 + 0] = inr;
    stats[i * 4 + 1] = ini;
    stats[i * 4 + 2] = picked;
    stats[i * 4 + 3] = mx + logf(den);
  }
}

// ---------------- K1b: tiled transpose s[8192][256] -> sT[256][8192] ----------------
__global__ __launch_bounds__(256) void k_transpose(
    const __hip_bfloat16* __restrict__ s, __hip_bfloat16* __restrict__ sT)
{
  __shared__ __hip_bfloat16 tile[64][72];   // +8 pad breaks bank alignment
  const int t = threadIdx.x;
  const int n0 = blockIdx.x * 64, f0 = blockIdx.y * 64;
  const int r = t >> 2, c = t & 3;
  const bf16x8 v0 = *(const bf16x8*)(s + (size_t)(n0 + r) * 256 + f0 + c * 16);
  const bf16x8 v1 = *(const bf16x8*)(s + (size_t)(n0 + r) * 256 + f0 + c * 16 + 8);
  *(bf16x8*)&tile[r][c * 16] = v0;
  *(bf16x8*)&tile[r][c * 16 + 8] = v1;
  __syncthreads();
  const int fr = t >> 2, nc = t & 3;
  __hip_bfloat16 o[16];
#pragma unroll
  for (int j = 0; j < 16; j++) o[j] = tile[nc * 16 + j][fr];
  *(bf16x8*)(sT + (size_t)(f0 + fr) * NN + n0 + nc * 16) = *(const bf16x8*)&o[0];
  *(bf16x8*)(sT + (size_t)(f0 + fr) * NN + n0 + nc * 16 + 8) = *(const bf16x8*)&o[8];
}

// ---------------- K2: build combined MLP weight, transposed, bf16 ----------------
__global__ __launch_bounds__(256) void k_build_bt(
    const float* __restrict__ Wr, const float* __restrict__ Wi,
    __hip_bfloat16* __restrict__ BT)
{
  const int tid = blockIdx.x * 256 + threadIdx.x;  // 65536
  const int n = tid >> 8, k = tid & 255;
  float v;
  if (n < 128) {
    v = (k < 128) ? Wr[n * 128 + k] : -Wi[n * 128 + (k - 128)];
  } else {
    v = (k < 128) ? Wi[(n - 128) * 128 + k] : Wr[(n - 128) * 128 + (k - 128)];
  }
  BT[tid] = __float2bfloat16(v);
}

// ---------------- K3: FUSED adj-GEMM + complex scale + MLP + bias + residual ----------
// grid 256 blocks (M-tile 32, full N=256 per block, no split-K -> no part[] round-trip).
// Wave w owns output cols {w*32..+31} (real) and {128+w*32..+31} (imag), so the
// (real,imag) pair needed for the complex scale lives in the SAME lane.
// Main loop: T3-minimum pipeline (dbuf LDS, 1 raw barrier/K-step, loads in flight).
// Epilogue: scale by (in_r,in_i), cvt bf16 -> msgS in LDS, then 256x256 MLP with
// BT fragments read directly from global (128 KB, L2-resident), bias+residual, store.
__global__ __launch_bounds__(256) void k_fused(
    const float* __restrict__ adj,            // [8192][8192] f32
    const __hip_bfloat16* __restrict__ sT,    // [256][8192] bf16
    const float* __restrict__ stats,          // [8192][4]
    const __hip_bfloat16* __restrict__ BT,    // [256][256] bf16
    const float* __restrict__ br, const float* __restrict__ bi,
    const float* __restrict__ xr, const float* __restrict__ xi,
    float* __restrict__ out)                  // new_r @0, new_i @ NN*DD (f32)
{
  // [0,8K)   As: 2 bufs x [ks=2][32][32] bf16
  // [8K,72K) Bs: 2 bufs x [ks=2][256][32] bf16
  // post-phase: msgS 8 chunks x [32][32] bf16 (16 KB) overlays [8K,24K)
  __shared__ __align__(16) char lds[73728];
  __hip_bfloat16* As = (__hip_bfloat16*)lds;
  __hip_bfloat16* Bs = (__hip_bfloat16*)(lds + 8192);
  __hip_bfloat16* msgS = (__hip_bfloat16*)(lds + 8192);

  const int t = threadIdx.x;
  const int w = t >> 6;
  const int lane = t & 63;
  const int lm = lane & 15, kq = lane >> 4;
  const int m0 = blockIdx.x * 32;

  // column mapping: nt=0,1 -> real cols w*32+nt*16 ; nt=2,3 -> imag cols 128+w*32+(nt-2)*16
  int ncol[4];
  ncol[0] = w * 32;       ncol[1] = w * 32 + 16;
  ncol[2] = 128 + w * 32; ncol[3] = 128 + w * 32 + 16;

  // A staging: thread t covers row t>>3, k-cols (t&7)*8..+7 (8 f32 -> 8 bf16, one ks half)
  const float* adjp = adj + (size_t)(m0 + (t >> 3)) * NN + (t & 7) * 8;
  const int aoff = ((t & 7) >> 2) * 1024 + (t >> 3) * 32 + ((t & 7) & 3) * 8;

  // B staging: slot p = q*256+t in [0,2048): ks=p>>10, n=(p>>2)&255, sub=p&3
  const __hip_bfloat16* srcB[8];
#pragma unroll
  for (int q = 0; q < 8; q++) {
    const int p = q * 256 + t;
    srcB[q] = sT + (size_t)((p >> 2) & 255) * NN + (p >> 10) * 32 + (p & 3) * 8;
  }

  f32x4 acc[2][4];
#pragma unroll
  for (int a = 0; a < 2; a++)
#pragma unroll
    for (int b = 0; b < 4; b++) acc[a][b] = (f32x4){0.f, 0.f, 0.f, 0.f};

  // ---- prologue: stage tile 0 into buffer 0 ----
  {
    const float4 a0 = *(const float4*)(adjp);
    const float4 a1 = *(const float4*)(adjp + 4);
#pragma unroll
    for (int q = 0; q < 8; q++)
      gload16(srcB[q], (char*)Bs + (q * 256 + t) * 16);
    *(bf16x4*)&As[aoff]     = cvt4(a0.x, a0.y, a0.z, a0.w);
    *(bf16x4*)&As[aoff + 4] = cvt4(a1.x, a1.y, a1.z, a1.w);
    asm volatile("s_waitcnt vmcnt(0) lgkmcnt(0)" ::: "memory");
    __builtin_amdgcn_s_barrier();
  }

#pragma unroll 2
  for (int kt = 0; kt < 128; kt++) {
    const int cur = kt & 1;
    const int nxt = cur ^ 1;
    float4 a0, a1;
    if (kt + 1 < 128) {
      const int knx = (kt + 1) * 64;
      a0 = *(const float4*)(adjp + knx);
      a1 = *(const float4*)(adjp + knx + 4);
#pragma unroll
      for (int q = 0; q < 8; q++)
        gload16(srcB[q] + knx, (char*)Bs + (nxt * 2048 + q * 256 + t) * 16);
    }
    // ---- compute current tile ----
#pragma unroll
    for (int ks = 0; ks < 2; ks++) {
      bf16x8 av[2], bv[4];
      av[0] = *(const bf16x8*)&As[cur * 2048 + ks * 1024 + lm * 32 + kq * 8];
      av[1] = *(const bf16x8*)&As[cur * 2048 + ks * 1024 + (16 + lm) * 32 + kq * 8];
#pragma unroll
      for (int nt = 0; nt < 4; nt++)
        bv[nt] = *(const bf16x8*)&Bs[cur * 16384 + ks * 8192 + (ncol[nt] + lm) * 32 + kq * 8];
      __builtin_amdgcn_s_setprio(1);
#pragma unroll
      for (int mt = 0; mt < 2; mt++)
#pragma unroll
        for (int nt = 0; nt < 4; nt++)
          acc[mt][nt] = __builtin_amdgcn_mfma_f32_16x16x32_bf16(av[mt], bv[nt], acc[mt][nt], 0, 0, 0);
      __builtin_amdgcn_s_setprio(0);
    }
    // ---- publish next A tile ----
    if (kt + 1 < 128) {
      *(bf16x4*)&As[nxt * 2048 + aoff]     = cvt4(a0.x, a0.y, a0.z, a0.w);
      *(bf16x4*)&As[nxt * 2048 + aoff + 4] = cvt4(a1.x, a1.y, a1.z, a1.w);
    }
    asm volatile("s_waitcnt vmcnt(0) lgkmcnt(0)" ::: "memory");
    __builtin_amdgcn_s_barrier();
  }
  // ---- complex scale in-register, write msgS (bf16, k-chunked for MLP A-frags) ----
  float inr_[2][4], ini_[2][4];
#pragma unroll
  for (int mt = 0; mt < 2; mt++)
#pragma unroll
    for (int r = 0; r < 4; r++) {
      const int i = m0 + mt * 16 + kq * 4 + r;   // C/D layout: row = (lane>>4)*4 + reg
      inr_[mt][r] = stats[i * 4 + 0];
      ini_[mt][r] = stats[i * 4 + 1];
    }
#pragma unroll
  for (int mt = 0; mt < 2; mt++)
#pragma unroll
    for (int nt = 0; nt < 2; nt++)
#pragma unroll
      for (int r = 0; r < 4; r++) {
        const float ar = acc[mt][nt][r], ai = acc[mt][nt + 2][r];
        const float mr = inr_[mt][r] * ar - ini_[mt][r] * ai;
        const float mi = inr_[mt][r] * ai + ini_[mt][r] * ar;
        const int i = mt * 16 + kq * 4 + r;          // 0..31 (tile-local row)
        const int cc = nt * 16 + lm;                 // 0..31 (within col chunk)
        msgS[w * 1024 + i * 32 + cc]       = __float2bfloat16(mr);   // chunk kc=w (real)
        msgS[(4 + w) * 1024 + i * 32 + cc] = __float2bfloat16(mi);   // chunk kc=4+w (imag)
      }
  __syncthreads();

  // ---- MLP: out[32][256] = msg[32][256] @ BT^T ; BT frags straight from global (L2-hot)
  const __hip_bfloat16* btp[4];
#pragma unroll
  for (int nt = 0; nt < 4; nt++)
    btp[nt] = BT + (size_t)(ncol[nt] + lm) * 256 + kq * 8;

  f32x4 acc2[2][4];
#pragma unroll
  for (int a = 0; a < 2; a++)
#pragma unroll
    for (int b = 0; b < 4; b++) acc2[a][b] = (f32x4){0.f, 0.f, 0.f, 0.f};

#pragma unroll
  for (int kc = 0; kc < 8; kc++) {
    bf16x8 av[2], bv[4];
    av[0] = *(const bf16x8*)&msgS[kc * 1024 + lm * 32 + kq * 8];
    av[1] = *(const bf16x8*)&msgS[kc * 1024 + (16 + lm) * 32 + kq * 8];
#pragma unroll
    for (int nt = 0; nt < 4; nt++)
      bv[nt] = *(const bf16x8*)(btp[nt] + kc * 32);
#pragma unroll
    for (int mt = 0; mt < 2; mt++)
#pragma unroll
      for (int nt = 0; nt < 4; nt++)
        acc2[mt][nt] = __builtin_amdgcn_mfma_f32_16x16x32_bf16(av[mt], bv[nt], acc2[mt][nt], 0, 0, 0);
  }

  // ---- bias + residual + store ----
#pragma unroll
  for (int mt = 0; mt < 2; mt++)
#pragma unroll
    for (int nt = 0; nt < 4; nt++) {
      const int by = nt >> 1;                    // 0 -> real half, 1 -> imag half
      const int j = (ncol[nt] & 127) + lm;       // 0..127
      const float bb = br[j] + (by ? bi[j] : -bi[j]);
      const float* resid = by ? xi : xr;
#pragma unroll
      for (int r = 0; r < 4; r++) {
        const int i = m0 + mt * 16 + kq * 4 + r;
        out[(size_t)by * (NN * DD) + (size_t)i * DD + j] =
            acc2[mt][nt][r] + bb + resid[(size_t)i * DD + j];
      }
    }
}

// ---------------- K5: losses (f32 out) ----------------
__global__ __launch_bounds__(1024) void k_loss(
    const float* __restrict__ thi, const int* __restrict__ tix,
    const float* __restrict__ stats, float* __restrict__ out2)
{
  __shared__ float red[16];
  const int t = threadIdx.x;
  const int idx = tix[t];
  float v = stats[idx * 4 + 2] - stats[idx * 4 + 3];  // logp at label = picked - lse
#pragma unroll
  for (int off = 32; off > 0; off >>= 1) v += __shfl_xor(v, off, 64);
  if ((t & 63) == 0) red[t >> 6] = v;
  __syncthreads();
  if (t == 0) {
    float s = 0.f;
    for (int q = 0; q < 16; q++) s += red[q];
    const float sup = -0.1f * (s / (float)TT);
    float th[CC];
    for (int c = 0; c < CC; c++) th[c] = thi[c];
    for (int a = 1; a < CC; a++) {        // insertion sort ascending
      const float key = th[a];
      int b = a - 1;
      while (b >= 0 && th[b] > key) { th[b + 1] = th[b]; b--; }
      th[b + 1] = key;
    }
    float dsum = 0.f, dmax = 0.f;
    for (int a = 0; a < CC - 1; a++) {
      const float d = fabsf(th[a] - th[a + 1]);
      dsum += d;
      dmax = fmaxf(dmax, d);
    }
    const float difference = dsum / (dmax + 1e-6f);
    out2[0] = 0.1f / (1e-6f + difference);  // separate_loss
    out2[1] = sup;                          // supervised_loss
  }
}

extern "C" void kernel_launch(void* const* d_in, const int* in_sizes, int n_in,
                              void* d_out, int out_size, void* d_ws, size_t ws_size,
                              hipStream_t stream) {
  const float* xr  = (const float*)d_in[0];
  const float* xi  = (const float*)d_in[1];
  const float* adj = (const float*)d_in[2];
  const float* thr = (const float*)d_in[3];
  const float* thi = (const float*)d_in[4];
  const float* Wr  = (const float*)d_in[5];
  const float* br  = (const float*)d_in[6];
  const float* Wi  = (const float*)d_in[7];
  const float* bi  = (const float*)d_in[8];
  const float* Wcr = (const float*)d_in[9];
  const float* bcr = (const float*)d_in[10];
  const float* Wci = (const float*)d_in[11];
  const float* bci = (const float*)d_in[12];
  const int* labels = (const int*)d_in[13];
  const int* tix    = (const int*)d_in[14];
  float* out = (float*)d_out;

  // workspace layout (~8.3 MB):
  //   [0,4MB)          s [8192][256] bf16 (row-major)
  //   [4,8MB)          sT [256][8192] bf16
  //   [8MB,+128K)      stats [8192][4] f32
  //   [8MB+128K,+128K) BT [256][256] bf16
  char* ws = (char*)d_ws;
  __hip_bfloat16* s    = (__hip_bfloat16*)(ws);
  __hip_bfloat16* sT   = (__hip_bfloat16*)(ws + (size_t)4 * 1024 * 1024);
  float*          stats= (float*)(ws + (size_t)8 * 1024 * 1024);
  __hip_bfloat16* BT   = (__hip_bfloat16*)(ws + (size_t)8 * 1024 * 1024 + 131072);

  k_head<<<NN / 4, 256, 0, stream>>>(xr, xi, Wcr, bcr, Wci, bci, thr, thi, labels, s, stats);
  k_transpose<<<dim3(NN / 64, 4), 256, 0, stream>>>(s, sT);
  k_build_bt<<<256, 256, 0, stream>>>(Wr, Wi, BT);
  k_fused<<<256, 256, 0, stream>>>(adj, sT, stats, BT, br, bi, xr, xi, out);
  k_loss<<<1, TT, 0, stream>>>(thi, tix, stats, out + (size_t)2 * NN * DD);
}